// Round 7
// baseline (654.220 us; speedup 1.0000x reference)
//
#include <hip/hip_runtime.h>
#include <hip/hip_bf16.h>
#include <math.h>

#define IN_CH 128
#define HID 64
#define OUT_CH 40

typedef const __hip_bfloat16* bf16p;
typedef __attribute__((ext_vector_type(8))) short v8s;
typedef __attribute__((ext_vector_type(4))) float v4f;

// ---- flag detection: flags[0]=1 if float tensors are f32, flags[1]=1 if indices are int64
__global__ void k_detect(const void* x, const void* ei, int* flags) {
    __shared__ int s_f32, s_hi;
    if (threadIdx.x == 0) { s_f32 = 0; s_hi = 0; }
    __syncthreads();
    const __hip_bfloat16* xb = (const __hip_bfloat16*)x;
    const int* ii = (const int*)ei;
    int lf = 0, lh = 0;
    for (int i = threadIdx.x; i < 4096; i += blockDim.x) {
        float f = __bfloat162float(xb[i]);
        if (!(fabsf(f) <= 1e4f)) lf = 1;       // huge/NaN -> buffer is really f32
        lh |= ii[2 * i + 1];                    // int64 high words are all zero
    }
    if (lf) atomicOr(&s_f32, 1);
    if (lh) atomicOr(&s_hi, 1);
    __syncthreads();
    if (threadIdx.x == 0) { flags[0] = s_f32 ? 1 : 0; flags[1] = (s_hi == 0) ? 1 : 0; }
}

// ---- weights to f32 table wf = [W1f 8192 | b1f 64 | W2f 2560 | b2f 40],
//      plus W1 packed into MFMA B-fragment order (bf16):
//      w1frag[((kb*4+cb)*64+lane)*8+j] = W1[kb*32+(lane>>4)*8+j][cb*16+(lane&15)]
__global__ void k_convw(const void* W1, const void* b1, const void* W2, const void* b2,
                        const int* flags, float* wf, __hip_bfloat16* w1frag) {
    int i = blockIdx.x * blockDim.x + threadIdx.x;
    if (i >= 19048) return;
    int isF32 = flags[0];
    if (i < 10856) {
        const void* src; int off;
        if (i < 8192)       { src = W1; off = i; }
        else if (i < 8256)  { src = b1; off = i - 8192; }
        else if (i < 10816) { src = W2; off = i - 8256; }
        else                { src = b2; off = i - 10816; }
        float v;
        if (isF32) v = ((const float*)src)[off];
        else       v = __bfloat162float(((bf16p)src)[off]);
        wf[i] = v;
    } else {
        int t = i - 10856;
        int j = t & 7, lane = (t >> 3) & 63, cb = (t >> 9) & 3, kb = t >> 11;
        int k = kb * 32 + ((lane >> 4) & 3) * 8 + j;
        int c = cb * 16 + (lane & 15);
        float v;
        if (isF32) v = ((const float*)W1)[k * HID + c];
        else       v = __bfloat162float(((bf16p)W1)[k * HID + c]);
        w1frag[t] = __float2bfloat16(v);
    }
}

// ---- in-degree histogram over col (int)
__global__ void k_deg(const int* ei, const int* flags, int* deg, int E) {
    int e = blockIdx.x * blockDim.x + threadIdx.x;
    if (e >= E) return;
    int c;
    if (flags[1]) c = ei[2 * (E + e)];
    else          c = ei[E + e];
    atomicAdd(&deg[c], 1);
}

__global__ void k_dinv(const int* deg, float* dinv, int N) {
    int i = blockIdx.x * blockDim.x + threadIdx.x;
    if (i >= N) return;
    dinv[i] = rsqrtf((float)deg[i] + 1.0f);   // +1 = self-loop
}

// ---- exclusive scan over deg -> rowstart (3 kernels)
__global__ void k_blocksum(const int* deg, int* bsum, int N) {
    __shared__ int s[256];
    int i = blockIdx.x * 256 + threadIdx.x;
    s[threadIdx.x] = (i < N) ? deg[i] : 0;
    __syncthreads();
    for (int off = 128; off > 0; off >>= 1) {
        if (threadIdx.x < off) s[threadIdx.x] += s[threadIdx.x + off];
        __syncthreads();
    }
    if (threadIdx.x == 0) bsum[blockIdx.x] = s[0];
}

__global__ void k_scanbsum(int* bsum, int NB) {
    __shared__ int s[1024];
    __shared__ int carry_s;
    if (threadIdx.x == 0) carry_s = 0;
    __syncthreads();
    for (int base = 0; base < NB; base += 1024) {
        int i = base + threadIdx.x;
        int v = (i < NB) ? bsum[i] : 0;
        s[threadIdx.x] = v;
        __syncthreads();
        for (int off = 1; off < 1024; off <<= 1) {
            int t = (threadIdx.x >= off) ? s[threadIdx.x - off] : 0;
            __syncthreads();
            s[threadIdx.x] += t;
            __syncthreads();
        }
        int total = s[1023];
        int excl = s[threadIdx.x] - v + carry_s;
        if (i < NB) bsum[i] = excl;
        __syncthreads();
        if (threadIdx.x == 0) carry_s += total;
        __syncthreads();
    }
}

__global__ void k_scanfinal(const int* deg, const int* boff, int* rowstart, int N) {
    __shared__ int s[256];
    int i = blockIdx.x * 256 + threadIdx.x;
    int v = (i < N) ? deg[i] : 0;
    s[threadIdx.x] = v;
    __syncthreads();
    for (int off = 1; off < 256; off <<= 1) {
        int t = (threadIdx.x >= off) ? s[threadIdx.x - off] : 0;
        __syncthreads();
        s[threadIdx.x] += t;
        __syncthreads();
    }
    if (i < N) rowstart[i] = boff[blockIdx.x] + s[threadIdx.x] - v;
    if (i == N - 1) rowstart[N] = boff[blockIdx.x] + s[threadIdx.x];
}

// ---- bucket-scatter edges into CSR, XCD-sliced: slice = blockIdx & 7 owns
//      destinations [slice*N/8,(slice+1)*N/8) so erow writes stay in one XCD's L2.
__global__ void k_scatter(const int* ei, const int* flags, const int* rowstart,
                          int* fill, int* erow, int E, int N) {
    int slice = blockIdx.x & 7;
    int nlo = (int)(((long)N * slice) >> 3);
    int nhi = (int)(((long)N * (slice + 1)) >> 3);
    int nblk = gridDim.x >> 3;
    int bid = blockIdx.x >> 3;
    int i64 = flags[1];
    for (int e = bid * 256 + threadIdx.x; e < E; e += nblk * 256) {
        int r, c;
        if (i64) { r = ei[2 * e]; c = ei[2 * (E + e)]; }
        else     { r = ei[e];     c = ei[E + e]; }
        if (c >= nlo && c < nhi) {
            int pos = rowstart[c] + atomicAdd(&fill[c], 1);
            erow[pos] = r;
        }
    }
}

// ---- GEMM1 via MFMA, cb-outer structure (low VGPR pressure): one wave per 16-node tile.
//      A-frags (4, loop-invariant) from x; per channel-block: 4 B-frags reloaded from
//      L2-resident w1frag, 4 chained MFMAs, store. Live regs ~50 -> no spill.
__global__ __launch_bounds__(256) void k_gemm1(const void* x, const float* wf,
                                               const __hip_bfloat16* w1frag,
                                               __hip_bfloat16* h1b, const int* flags, int N) {
    const int isF32 = flags[0];
    const int lane = threadIdx.x & 63;
    const int wid = blockIdx.x * 4 + (threadIdx.x >> 6);
    if (!isF32) {
        const int ntiles = (N + 15) / 16;
        if (wid >= ntiles) return;
        const int m = lane & 15, quad = lane >> 4;
        const short* wfr = (const short*)w1frag;
        const int nbase = wid * 16;
        int node = nbase + m; if (node >= N) node = N - 1;
        const short* xrow = (const short*)x + (size_t)node * IN_CH + quad * 8;
        v8s a0 = *(const v8s*)(xrow);
        v8s a1 = *(const v8s*)(xrow + 32);
        v8s a2 = *(const v8s*)(xrow + 64);
        v8s a3 = *(const v8s*)(xrow + 96);
        #pragma unroll
        for (int cb = 0; cb < 4; ++cb) {
            v8s b0 = *(const v8s*)(wfr + (((0 + cb) * 64 + lane) * 8));
            v8s b1 = *(const v8s*)(wfr + (((4 + cb) * 64 + lane) * 8));
            v8s b2 = *(const v8s*)(wfr + (((8 + cb) * 64 + lane) * 8));
            v8s b3 = *(const v8s*)(wfr + (((12 + cb) * 64 + lane) * 8));
            v4f acc = {0.f, 0.f, 0.f, 0.f};
            acc = __builtin_amdgcn_mfma_f32_16x16x32_bf16(a0, b0, acc, 0, 0, 0);
            acc = __builtin_amdgcn_mfma_f32_16x16x32_bf16(a1, b1, acc, 0, 0, 0);
            acc = __builtin_amdgcn_mfma_f32_16x16x32_bf16(a2, b2, acc, 0, 0, 0);
            acc = __builtin_amdgcn_mfma_f32_16x16x32_bf16(a3, b3, acc, 0, 0, 0);
            #pragma unroll
            for (int reg = 0; reg < 4; ++reg) {
                int n = nbase + quad * 4 + reg;
                if (n < N)
                    h1b[(size_t)n * HID + cb * 16 + m] = __float2bfloat16(acc[reg]);
            }
        }
    } else {
        // f32 fallback (VALU)
        const int c = lane;
        const int nwaves = gridDim.x * 4;
        for (int n = wid; n < N; n += nwaves) {
            const float* xr = (const float*)x + (size_t)n * IN_CH;
            float acc = 0.f;
            #pragma unroll 8
            for (int k = 0; k < IN_CH; ++k) acc += xr[k] * wf[k * HID + c];
            h1b[(size_t)n * HID + c] = __float2bfloat16(acc);
        }
    }
}

// ---- Fused aggregation1 (+self-loop+bias+ReLU) AND GEMM2: one wave per node.
__global__ __launch_bounds__(256) void k_agg1gemm2(const int* rowstart, const int* erow,
        const __hip_bfloat16* h1b, const float* dinv, const float* b1f, const float* w2f,
        float* h2, int N) {
    __shared__ float w2[HID * OUT_CH];   // 2560 floats
    __shared__ float sg[256];            // per-wave g slices
    for (int i = threadIdx.x; i < HID * OUT_CH; i += 256) w2[i] = w2f[i];
    __syncthreads();

    int w = (blockIdx.x * 256 + threadIdx.x) >> 6;
    int c = threadIdx.x & 63;
    bool act = (w < N);
    float g = 0.f;
    if (act) {
        int s0 = __builtin_amdgcn_readfirstlane(rowstart[w]);
        int s1 = __builtin_amdgcn_readfirstlane(rowstart[w + 1]);
        float d = dinv[w];
        float acc = __bfloat162float(h1b[(size_t)w * HID + c]) * d * d + b1f[c];
        int i = s0;
        for (; i + 1 < s1; i += 2) {
            int r0 = erow[i];     int r1 = erow[i + 1];
            float n0 = dinv[r0] * d;
            float n1 = dinv[r1] * d;
            float v0 = __bfloat162float(h1b[(size_t)r0 * HID + c]);
            float v1 = __bfloat162float(h1b[(size_t)r1 * HID + c]);
            acc += v0 * n0 + v1 * n1;
        }
        if (i < s1) {
            int r = erow[i];
            acc += __bfloat162float(h1b[(size_t)r * HID + c]) * (dinv[r] * d);
        }
        g = fmaxf(acc, 0.f);
    }
    sg[threadIdx.x] = g;
    __syncthreads();
    if (act && c < OUT_CH) {
        const float* gs = sg + (threadIdx.x & 192);   // this wave's 64-slice
        float acc2 = 0.f;
        #pragma unroll
        for (int k = 0; k < HID; ++k) acc2 += gs[k] * w2[k * OUT_CH + c];
        h2[(size_t)w * OUT_CH + c] = acc2;
    }
}

// ---- Aggregation 2 (CSR): one wave per node, lanes 0..39 = channels; fused final -> d_out
__global__ __launch_bounds__(256) void k_agg2_csr(const int* rowstart, const int* erow,
        const float* h2, const float* dinv, const float* b2f, float* out, int N) {
    int w = (blockIdx.x * 256 + threadIdx.x) >> 6;
    int c = threadIdx.x & 63;
    if (w >= N) return;
    int s0 = __builtin_amdgcn_readfirstlane(rowstart[w]);
    int s1 = __builtin_amdgcn_readfirstlane(rowstart[w + 1]);
    float d = dinv[w];
    float acc = 0.f;
    if (c < OUT_CH) acc = h2[(size_t)w * OUT_CH + c] * d * d + b2f[c];
    int i = s0;
    for (; i + 1 < s1; i += 2) {
        int r0 = erow[i];     int r1 = erow[i + 1];
        float n0 = dinv[r0] * d;
        float n1 = dinv[r1] * d;
        if (c < OUT_CH) {
            float v0 = h2[(size_t)r0 * OUT_CH + c];
            float v1 = h2[(size_t)r1 * OUT_CH + c];
            acc += v0 * n0 + v1 * n1;
        }
    }
    if (i < s1 && c < OUT_CH) {
        int r = erow[i];
        acc += h2[(size_t)r * OUT_CH + c] * (dinv[r] * d);
    }
    if (c < OUT_CH) out[(size_t)w * OUT_CH + c] = acc;
}

extern "C" void kernel_launch(void* const* d_in, const int* in_sizes, int n_in,
                              void* d_out, int out_size, void* d_ws, size_t ws_size,
                              hipStream_t stream) {
    const void* x  = d_in[0];
    const void* ei = d_in[1];
    const void* W1 = d_in[2];
    const void* b1 = d_in[3];
    const void* W2 = d_in[4];
    const void* b2 = d_in[5];
    const int N = in_sizes[0] / IN_CH;   // 100000
    const int E = in_sizes[1] / 2;       // 1600000
    const int* eii = (const int*)ei;
    const int NB = (N + 255) / 256;

    // ---- workspace layout (4-byte units). Peak ≈ 37 MiB.
    float* ws = (float*)d_ws;
    size_t off = 16;
    int*   flags    = (int*)ws;
    int*   deg      = (int*)ws + off;            off += N;
    int*   fill     = (int*)ws + off;            off += N;   // contiguous with deg: one memset
    float* dinv     = ws + off;                  off += N;
    float* wf       = ws + off;                  off += 10880;
    __hip_bfloat16* w1frag = (__hip_bfloat16*)(ws + off);  off += 4096;  // 8192 bf16
    int*   bsum     = (int*)ws + off;            off += NB + 16;
    int*   rowstart = (int*)ws + off;            off += N + 1;
    off = (off + 255) & ~(size_t)255;
    int*   erow     = (int*)ws + off;            off += E;
    __hip_bfloat16* h1b = (__hip_bfloat16*)(ws + off);     off += (size_t)N * HID / 2;
    float* h2       = ws + off;                  off += (size_t)N * OUT_CH;

    hipMemsetAsync(deg, 0, (size_t)2 * N * sizeof(int), stream);  // deg + fill

    k_detect<<<1, 256, 0, stream>>>(x, ei, flags);
    k_convw<<<(19048 + 255) / 256, 256, 0, stream>>>(W1, b1, W2, b2, flags, wf, w1frag);
    k_deg<<<(E + 255) / 256, 256, 0, stream>>>(eii, flags, deg, E);
    k_dinv<<<(N + 255) / 256, 256, 0, stream>>>(deg, dinv, N);

    k_blocksum<<<NB, 256, 0, stream>>>(deg, bsum, N);
    k_scanbsum<<<1, 1024, 0, stream>>>(bsum, NB);
    k_scanfinal<<<NB, 256, 0, stream>>>(deg, bsum, rowstart, N);
    k_scatter<<<2048, 256, 0, stream>>>(eii, flags, rowstart, fill, erow, E, N);

    // one wave per 16-node tile: ntiles = ceil(N/16); 4 waves/block
    int ntiles = (N + 15) / 16;                  // 6250
    int g1blocks = (ntiles + 3) / 4;             // 1563
    k_gemm1<<<g1blocks, 256, 0, stream>>>(x, wf, w1frag, h1b, flags, N);

    int nodeBlocks = (N * 64 + 255) / 256;   // 25000
    k_agg1gemm2<<<nodeBlocks, 256, 0, stream>>>(rowstart, erow, h1b, dinv,
                                                wf + 8192, wf + 8256, h2, N);

    k_agg2_csr<<<nodeBlocks, 256, 0, stream>>>(rowstart, erow, h2, dinv,
                                               wf + 10816, (float*)d_out, N);
}

// Round 8
// 644.597 us; speedup vs baseline: 1.0149x; 1.0149x over previous
//
#include <hip/hip_runtime.h>
#include <hip/hip_bf16.h>
#include <math.h>

#define IN_CH 128
#define HID 64
#define OUT_CH 40

typedef const __hip_bfloat16* bf16p;
typedef __attribute__((ext_vector_type(8))) short v8s;
typedef __attribute__((ext_vector_type(4))) float v4f;

// ---- flag detection: flags[0]=1 if float tensors are f32, flags[1]=1 if indices are int64
__global__ void k_detect(const void* x, const void* ei, int* flags) {
    __shared__ int s_f32, s_hi;
    if (threadIdx.x == 0) { s_f32 = 0; s_hi = 0; }
    __syncthreads();
    const __hip_bfloat16* xb = (const __hip_bfloat16*)x;
    const int* ii = (const int*)ei;
    int lf = 0, lh = 0;
    for (int i = threadIdx.x; i < 4096; i += blockDim.x) {
        float f = __bfloat162float(xb[i]);
        if (!(fabsf(f) <= 1e4f)) lf = 1;       // huge/NaN -> buffer is really f32
        lh |= ii[2 * i + 1];                    // int64 high words are all zero
    }
    if (lf) atomicOr(&s_f32, 1);
    if (lh) atomicOr(&s_hi, 1);
    __syncthreads();
    if (threadIdx.x == 0) { flags[0] = s_f32 ? 1 : 0; flags[1] = (s_hi == 0) ? 1 : 0; }
}

// ---- weights to f32 table wf = [W1f 8192 | b1f 64 | W2f 2560 | b2f 40],
//      plus W1 packed into MFMA fragment order (bf16):
//      w1frag[((kb*4+cb)*64+lane)*8+j] = W1[kb*32+(lane>>4)*8+j][cb*16+(lane&15)]
//      (serves as the A-operand pack: lane&15 = channel-row m, quad*8+j = k)
__global__ void k_convw(const void* W1, const void* b1, const void* W2, const void* b2,
                        const int* flags, float* wf, __hip_bfloat16* w1frag) {
    int i = blockIdx.x * blockDim.x + threadIdx.x;
    if (i >= 19048) return;
    int isF32 = flags[0];
    if (i < 10856) {
        const void* src; int off;
        if (i < 8192)       { src = W1; off = i; }
        else if (i < 8256)  { src = b1; off = i - 8192; }
        else if (i < 10816) { src = W2; off = i - 8256; }
        else                { src = b2; off = i - 10816; }
        float v;
        if (isF32) v = ((const float*)src)[off];
        else       v = __bfloat162float(((bf16p)src)[off]);
        wf[i] = v;
    } else {
        int t = i - 10856;
        int j = t & 7, lane = (t >> 3) & 63, cb = (t >> 9) & 3, kb = t >> 11;
        int k = kb * 32 + ((lane >> 4) & 3) * 8 + j;
        int c = cb * 16 + (lane & 15);
        float v;
        if (isF32) v = ((const float*)W1)[k * HID + c];
        else       v = __bfloat162float(((bf16p)W1)[k * HID + c]);
        w1frag[t] = __float2bfloat16(v);
    }
}

// ---- in-degree histogram over col (int)
__global__ void k_deg(const int* ei, const int* flags, int* deg, int E) {
    int e = blockIdx.x * blockDim.x + threadIdx.x;
    if (e >= E) return;
    int c;
    if (flags[1]) c = ei[2 * (E + e)];
    else          c = ei[E + e];
    atomicAdd(&deg[c], 1);
}

__global__ void k_dinv(const int* deg, float* dinv, int N) {
    int i = blockIdx.x * blockDim.x + threadIdx.x;
    if (i >= N) return;
    dinv[i] = rsqrtf((float)deg[i] + 1.0f);   // +1 = self-loop
}

// ---- exclusive scan over deg -> rowstart (3 kernels)
__global__ void k_blocksum(const int* deg, int* bsum, int N) {
    __shared__ int s[256];
    int i = blockIdx.x * 256 + threadIdx.x;
    s[threadIdx.x] = (i < N) ? deg[i] : 0;
    __syncthreads();
    for (int off = 128; off > 0; off >>= 1) {
        if (threadIdx.x < off) s[threadIdx.x] += s[threadIdx.x + off];
        __syncthreads();
    }
    if (threadIdx.x == 0) bsum[blockIdx.x] = s[0];
}

__global__ void k_scanbsum(int* bsum, int NB) {
    __shared__ int s[1024];
    __shared__ int carry_s;
    if (threadIdx.x == 0) carry_s = 0;
    __syncthreads();
    for (int base = 0; base < NB; base += 1024) {
        int i = base + threadIdx.x;
        int v = (i < NB) ? bsum[i] : 0;
        s[threadIdx.x] = v;
        __syncthreads();
        for (int off = 1; off < 1024; off <<= 1) {
            int t = (threadIdx.x >= off) ? s[threadIdx.x - off] : 0;
            __syncthreads();
            s[threadIdx.x] += t;
            __syncthreads();
        }
        int total = s[1023];
        int excl = s[threadIdx.x] - v + carry_s;
        if (i < NB) bsum[i] = excl;
        __syncthreads();
        if (threadIdx.x == 0) carry_s += total;
        __syncthreads();
    }
}

// rowstart + pre-seeded fill (saves a random load per edge in k_scatter)
__global__ void k_scanfinal(const int* deg, const int* boff, int* rowstart, int* fill, int N) {
    __shared__ int s[256];
    int i = blockIdx.x * 256 + threadIdx.x;
    int v = (i < N) ? deg[i] : 0;
    s[threadIdx.x] = v;
    __syncthreads();
    for (int off = 1; off < 256; off <<= 1) {
        int t = (threadIdx.x >= off) ? s[threadIdx.x - off] : 0;
        __syncthreads();
        s[threadIdx.x] += t;
        __syncthreads();
    }
    if (i < N) {
        int rs = boff[blockIdx.x] + s[threadIdx.x] - v;
        rowstart[i] = rs;
        fill[i] = rs;
    }
    if (i == N - 1) rowstart[N] = boff[blockIdx.x] + s[threadIdx.x];
}

// ---- bucket-scatter edges into CSR, XCD-sliced: slice = blockIdx & 7 owns
//      destinations [slice*N/8,(slice+1)*N/8) so erow writes stay in one XCD's L2.
__global__ void k_scatter(const int* ei, const int* flags, int* fill, int* erow,
                          int E, int N) {
    int slice = blockIdx.x & 7;
    int nlo = (int)(((long)N * slice) >> 3);
    int nhi = (int)(((long)N * (slice + 1)) >> 3);
    int nblk = gridDim.x >> 3;
    int bid = blockIdx.x >> 3;
    int i64 = flags[1];
    for (int e = bid * 256 + threadIdx.x; e < E; e += nblk * 256) {
        int r, c;
        if (i64) { r = ei[2 * e]; c = ei[2 * (E + e)]; }
        else     { r = ei[e];     c = ei[E + e]; }
        if (c >= nlo && c < nhi) {
            int pos = atomicAdd(&fill[c], 1);
            erow[pos] = r;
        }
    }
}

// ---- GEMM1 via MFMA, orientation-swapped (A=W1 from LDS, B=x), persistent waves
//      with 1-tile lookahead prefetch. D[row=channel quad*4+reg][col=node lane&15]
//      -> per cb one 8-byte store of 4 consecutive channels.
__global__ __launch_bounds__(256) void k_gemm1(const void* x, const float* wf,
                                               const __hip_bfloat16* w1frag,
                                               __hip_bfloat16* h1b, const int* flags, int N) {
    __shared__ short w1s[8192];   // 16 frags x 64 lanes x 8 bf16 = 16 KB
    {
        const int* s = (const int*)w1frag;
        int* d = (int*)w1s;
        for (int i = threadIdx.x; i < 4096; i += 256) d[i] = s[i];
    }
    __syncthreads();
    const int lane = threadIdx.x & 63;
    if (!flags[0]) {
        const int ntiles = (N + 15) >> 4;
        const int nidx = lane & 15, quad = lane >> 4;
        int tile = blockIdx.x * 4 + (threadIdx.x >> 6);
        const int stride = gridDim.x * 4;
        if (tile >= ntiles) return;
        const short* xb = (const short*)x;
        v8s cur0, cur1, cur2, cur3, nxt0, nxt1, nxt2, nxt3;
        {
            int node = tile * 16 + nidx; if (node >= N) node = N - 1;
            const short* xr = xb + (size_t)node * IN_CH + quad * 8;
            cur0 = *(const v8s*)(xr);
            cur1 = *(const v8s*)(xr + 32);
            cur2 = *(const v8s*)(xr + 64);
            cur3 = *(const v8s*)(xr + 96);
        }
        while (true) {
            int tnext = tile + stride;
            if (tnext < ntiles) {
                int node = tnext * 16 + nidx; if (node >= N) node = N - 1;
                const short* xr = xb + (size_t)node * IN_CH + quad * 8;
                nxt0 = *(const v8s*)(xr);
                nxt1 = *(const v8s*)(xr + 32);
                nxt2 = *(const v8s*)(xr + 64);
                nxt3 = *(const v8s*)(xr + 96);
            }
            int snode = tile * 16 + nidx;
            #pragma unroll
            for (int cb = 0; cb < 4; ++cb) {
                v4f acc = {0.f, 0.f, 0.f, 0.f};
                acc = __builtin_amdgcn_mfma_f32_16x16x32_bf16(
                        *(const v8s*)(w1s + ((0 * 4 + cb) * 64 + lane) * 8), cur0, acc, 0, 0, 0);
                acc = __builtin_amdgcn_mfma_f32_16x16x32_bf16(
                        *(const v8s*)(w1s + ((1 * 4 + cb) * 64 + lane) * 8), cur1, acc, 0, 0, 0);
                acc = __builtin_amdgcn_mfma_f32_16x16x32_bf16(
                        *(const v8s*)(w1s + ((2 * 4 + cb) * 64 + lane) * 8), cur2, acc, 0, 0, 0);
                acc = __builtin_amdgcn_mfma_f32_16x16x32_bf16(
                        *(const v8s*)(w1s + ((3 * 4 + cb) * 64 + lane) * 8), cur3, acc, 0, 0, 0);
                if (snode < N) {
                    union { __hip_bfloat16 h[4]; uint2 u; } pk;
                    pk.h[0] = __float2bfloat16(acc[0]);
                    pk.h[1] = __float2bfloat16(acc[1]);
                    pk.h[2] = __float2bfloat16(acc[2]);
                    pk.h[3] = __float2bfloat16(acc[3]);
                    *(uint2*)(h1b + (size_t)snode * HID + cb * 16 + quad * 4) = pk.u;
                }
            }
            tile = tnext;
            if (tile >= ntiles) break;
            cur0 = nxt0; cur1 = nxt1; cur2 = nxt2; cur3 = nxt3;
        }
    } else {
        // f32 fallback (VALU)
        const int c = lane;
        const int nwaves = gridDim.x * 4;
        for (int n = blockIdx.x * 4 + (threadIdx.x >> 6); n < N; n += nwaves) {
            const float* xr = (const float*)x + (size_t)n * IN_CH;
            float acc = 0.f;
            #pragma unroll 8
            for (int k = 0; k < IN_CH; ++k) acc += xr[k] * wf[k * HID + c];
            h1b[(size_t)n * HID + c] = __float2bfloat16(acc);
        }
    }
}

// ---- Aggregation 1 (CSR): one wave per node, lane=channel; self-loop+bias+ReLU;
//      output g as bf16 (gemm2 deferred past agg2 by linearity).
__global__ __launch_bounds__(256) void k_agg1(const int* rowstart, const int* erow,
        const __hip_bfloat16* h1b, const float* dinv, const float* b1f,
        __hip_bfloat16* gb, int N) {
    int w = (blockIdx.x * 256 + threadIdx.x) >> 6;
    int c = threadIdx.x & 63;
    if (w >= N) return;
    int s0 = __builtin_amdgcn_readfirstlane(rowstart[w]);
    int s1 = __builtin_amdgcn_readfirstlane(rowstart[w + 1]);
    float d = dinv[w];
    float acc = __bfloat162float(h1b[(size_t)w * HID + c]) * d * d + b1f[c];
    int i = s0;
    for (; i + 1 < s1; i += 2) {
        int r0 = erow[i];     int r1 = erow[i + 1];
        float n0 = dinv[r0] * d;
        float n1 = dinv[r1] * d;
        float v0 = __bfloat162float(h1b[(size_t)r0 * HID + c]);
        float v1 = __bfloat162float(h1b[(size_t)r1 * HID + c]);
        acc += v0 * n0 + v1 * n1;
    }
    if (i < s1) {
        int r = erow[i];
        acc += __bfloat162float(h1b[(size_t)r * HID + c]) * (dinv[r] * d);
    }
    gb[(size_t)w * HID + c] = __float2bfloat16(fmaxf(acc, 0.f));
}

// ---- Aggregation 2 (CSR) on g (64ch bf16), then W2+b2 epilogue in-wave -> d_out.
//      out[n][c] = (sum_edges norm*g[r] + d^2*g[n]) . W2[:,c] + b2[c]
__global__ __launch_bounds__(256) void k_agg2(const int* rowstart, const int* erow,
        const __hip_bfloat16* gb, const float* dinv, const float* w2f, const float* b2f,
        float* out, int N) {
    __shared__ float w2[HID * OUT_CH];   // 2560 floats
    __shared__ float sg[256];            // per-wave aggregated-g slices
    for (int i = threadIdx.x; i < HID * OUT_CH; i += 256) w2[i] = w2f[i];
    __syncthreads();
    int w = (blockIdx.x * 256 + threadIdx.x) >> 6;
    int c = threadIdx.x & 63;
    bool act = (w < N);
    float acc = 0.f;
    if (act) {
        int s0 = __builtin_amdgcn_readfirstlane(rowstart[w]);
        int s1 = __builtin_amdgcn_readfirstlane(rowstart[w + 1]);
        float d = dinv[w];
        acc = __bfloat162float(gb[(size_t)w * HID + c]) * d * d;
        int i = s0;
        for (; i + 1 < s1; i += 2) {
            int r0 = erow[i];     int r1 = erow[i + 1];
            float n0 = dinv[r0] * d;
            float n1 = dinv[r1] * d;
            float v0 = __bfloat162float(gb[(size_t)r0 * HID + c]);
            float v1 = __bfloat162float(gb[(size_t)r1 * HID + c]);
            acc += v0 * n0 + v1 * n1;
        }
        if (i < s1) {
            int r = erow[i];
            acc += __bfloat162float(gb[(size_t)r * HID + c]) * (dinv[r] * d);
        }
    }
    sg[threadIdx.x] = acc;
    __syncthreads();
    if (act && c < OUT_CH) {
        const float* gs = sg + (threadIdx.x & 192);   // this wave's 64-slice
        float o = b2f[c];
        #pragma unroll
        for (int k = 0; k < HID; ++k) o += gs[k] * w2[k * OUT_CH + c];
        out[(size_t)w * OUT_CH + c] = o;
    }
}

extern "C" void kernel_launch(void* const* d_in, const int* in_sizes, int n_in,
                              void* d_out, int out_size, void* d_ws, size_t ws_size,
                              hipStream_t stream) {
    const void* x  = d_in[0];
    const void* ei = d_in[1];
    const void* W1 = d_in[2];
    const void* b1 = d_in[3];
    const void* W2 = d_in[4];
    const void* b2 = d_in[5];
    const int N = in_sizes[0] / IN_CH;   // 100000
    const int E = in_sizes[1] / 2;       // 1600000
    const int* eii = (const int*)ei;
    const int NB = (N + 255) / 256;

    // ---- workspace layout (4-byte units). Peak ~33.7 MiB.
    float* ws = (float*)d_ws;
    size_t off = 16;
    int*   flags    = (int*)ws;
    int*   deg      = (int*)ws + off;            off += N;
    int*   fill     = (int*)ws + off;            off += N;
    float* dinv     = ws + off;                  off += N;
    float* wf       = ws + off;                  off += 10880;
    __hip_bfloat16* w1frag = (__hip_bfloat16*)(ws + off);  off += 4096;  // 8192 bf16
    int*   bsum     = (int*)ws + off;            off += NB + 16;
    int*   rowstart = (int*)ws + off;            off += N + 1;
    off = (off + 255) & ~(size_t)255;
    int*   erow     = (int*)ws + off;            off += E;
    __hip_bfloat16* h1b = (__hip_bfloat16*)(ws + off);     off += (size_t)N * HID / 2;
    __hip_bfloat16* gb  = (__hip_bfloat16*)(ws + off);     off += (size_t)N * HID / 2;

    hipMemsetAsync(deg, 0, (size_t)N * sizeof(int), stream);  // deg only; fill pre-seeded

    k_detect<<<1, 256, 0, stream>>>(x, ei, flags);
    k_convw<<<(19048 + 255) / 256, 256, 0, stream>>>(W1, b1, W2, b2, flags, wf, w1frag);
    k_deg<<<(E + 255) / 256, 256, 0, stream>>>(eii, flags, deg, E);
    k_dinv<<<(N + 255) / 256, 256, 0, stream>>>(deg, dinv, N);

    k_blocksum<<<NB, 256, 0, stream>>>(deg, bsum, N);
    k_scanbsum<<<1, 1024, 0, stream>>>(bsum, NB);
    k_scanfinal<<<NB, 256, 0, stream>>>(deg, bsum, rowstart, fill, N);
    k_scatter<<<4096, 256, 0, stream>>>(eii, flags, fill, erow, E, N);

    k_gemm1<<<512, 256, 0, stream>>>(x, wf, w1frag, h1b, flags, N);

    int nodeBlocks = (N * 64 + 255) / 256;   // 25000
    k_agg1<<<nodeBlocks, 256, 0, stream>>>(rowstart, erow, h1b, dinv, wf + 8192, gb, N);
    k_agg2<<<nodeBlocks, 256, 0, stream>>>(rowstart, erow, gb, dinv, wf + 8256,
                                           wf + 10816, (float*)d_out, N);
}

// Round 9
// 549.167 us; speedup vs baseline: 1.1913x; 1.1738x over previous
//
#include <hip/hip_runtime.h>
#include <hip/hip_bf16.h>
#include <math.h>

#define IN_CH 128
#define HID 64
#define OUT_CH 40

typedef const __hip_bfloat16* bf16p;

// ---- flag detection: flags[0]=1 if float tensors are f32, flags[1]=1 if indices are int64
__global__ void k_detect(const void* x, const void* ei, int* flags) {
    __shared__ int s_f32, s_hi;
    if (threadIdx.x == 0) { s_f32 = 0; s_hi = 0; }
    __syncthreads();
    const __hip_bfloat16* xb = (const __hip_bfloat16*)x;
    const int* ii = (const int*)ei;
    int lf = 0, lh = 0;
    for (int i = threadIdx.x; i < 4096; i += blockDim.x) {
        float f = __bfloat162float(xb[i]);
        if (!(fabsf(f) <= 1e4f)) lf = 1;       // huge/NaN -> buffer is really f32
        lh |= ii[2 * i + 1];                    // int64 high words are all zero
    }
    if (lf) atomicOr(&s_f32, 1);
    if (lh) atomicOr(&s_hi, 1);
    __syncthreads();
    if (threadIdx.x == 0) { flags[0] = s_f32 ? 1 : 0; flags[1] = (s_hi == 0) ? 1 : 0; }
}

// ---- convert weights/biases to f32: wf = [W1f 8192 | b1f 64 | W2f 2560 | b2f 40]
__global__ void k_convw(const void* W1, const void* b1, const void* W2, const void* b2,
                        const int* flags, float* wf) {
    int i = blockIdx.x * blockDim.x + threadIdx.x;
    if (i >= 10856) return;
    const void* src; int off;
    if (i < 8192)       { src = W1; off = i; }
    else if (i < 8256)  { src = b1; off = i - 8192; }
    else if (i < 10816) { src = W2; off = i - 8256; }
    else                { src = b2; off = i - 10816; }
    float v;
    if (flags[0]) v = ((const float*)src)[off];
    else          v = __bfloat162float(((bf16p)src)[off]);
    wf[i] = v;
}

// ---- in-degree histogram over col (int)
__global__ void k_deg(const int* ei, const int* flags, int* deg, int E) {
    int e = blockIdx.x * blockDim.x + threadIdx.x;
    if (e >= E) return;
    int c;
    if (flags[1]) c = ei[2 * (E + e)];
    else          c = ei[E + e];
    atomicAdd(&deg[c], 1);
}

__global__ void k_dinv(const int* deg, float* dinv, int N) {
    int i = blockIdx.x * blockDim.x + threadIdx.x;
    if (i >= N) return;
    dinv[i] = rsqrtf((float)deg[i] + 1.0f);   // +1 = self-loop
}

// ---- exclusive scan over deg -> rowstart (3 kernels)
__global__ void k_blocksum(const int* deg, int* bsum, int N) {
    __shared__ int s[256];
    int i = blockIdx.x * 256 + threadIdx.x;
    s[threadIdx.x] = (i < N) ? deg[i] : 0;
    __syncthreads();
    for (int off = 128; off > 0; off >>= 1) {
        if (threadIdx.x < off) s[threadIdx.x] += s[threadIdx.x + off];
        __syncthreads();
    }
    if (threadIdx.x == 0) bsum[blockIdx.x] = s[0];
}

__global__ void k_scanbsum(int* bsum, int NB) {
    __shared__ int s[1024];
    __shared__ int carry_s;
    if (threadIdx.x == 0) carry_s = 0;
    __syncthreads();
    for (int base = 0; base < NB; base += 1024) {
        int i = base + threadIdx.x;
        int v = (i < NB) ? bsum[i] : 0;
        s[threadIdx.x] = v;
        __syncthreads();
        for (int off = 1; off < 1024; off <<= 1) {
            int t = (threadIdx.x >= off) ? s[threadIdx.x - off] : 0;
            __syncthreads();
            s[threadIdx.x] += t;
            __syncthreads();
        }
        int total = s[1023];
        int excl = s[threadIdx.x] - v + carry_s;
        if (i < NB) bsum[i] = excl;
        __syncthreads();
        if (threadIdx.x == 0) carry_s += total;
        __syncthreads();
    }
}

// rowstart + pre-seeded fill (saves a random load per edge in k_scatter)
__global__ void k_scanfinal(const int* deg, const int* boff, int* rowstart, int* fill, int N) {
    __shared__ int s[256];
    int i = blockIdx.x * 256 + threadIdx.x;
    int v = (i < N) ? deg[i] : 0;
    s[threadIdx.x] = v;
    __syncthreads();
    for (int off = 1; off < 256; off <<= 1) {
        int t = (threadIdx.x >= off) ? s[threadIdx.x - off] : 0;
        __syncthreads();
        s[threadIdx.x] += t;
        __syncthreads();
    }
    if (i < N) {
        int rs = boff[blockIdx.x] + s[threadIdx.x] - v;
        rowstart[i] = rs;
        fill[i] = rs;
    }
    if (i == N - 1) rowstart[N] = boff[blockIdx.x] + s[threadIdx.x];
}

// ---- bucket-scatter edges into CSR, XCD-sliced; r loaded ONLY for passing edges
__global__ void k_scatter(const int* ei, const int* flags, int* fill, int* erow,
                          int E, int N) {
    int slice = blockIdx.x & 7;
    int nlo = (int)(((long)N * slice) >> 3);
    int nhi = (int)(((long)N * (slice + 1)) >> 3);
    int nblk = gridDim.x >> 3;
    int bid = blockIdx.x >> 3;
    int i64 = flags[1];
    for (int e = bid * 256 + threadIdx.x; e < E; e += nblk * 256) {
        int c;
        if (i64) c = ei[2 * (E + e)];
        else     c = ei[E + e];
        if (c >= nlo && c < nhi) {
            int r;
            if (i64) r = ei[2 * e];
            else     r = ei[e];
            int pos = atomicAdd(&fill[c], 1);
            erow[pos] = r;
        }
    }
}

// ---- GEMM1 (R5-proven structure): h1b[n][c] = bf16(sum_k x[n][k]*W1[k][c]);
//      W1 in LDS; one wave per node, lane = channel.
__global__ __launch_bounds__(256) void k_gemm1(const void* x, const float* W1f,
                                               __hip_bfloat16* h1b, const int* flags, int N) {
    __shared__ float w[IN_CH * HID];
    for (int i = threadIdx.x; i < IN_CH * HID; i += 256) w[i] = W1f[i];
    __syncthreads();
    const int isF32 = flags[0];
    const int c = threadIdx.x & 63;
    const int q = threadIdx.x >> 6;
    for (int n = blockIdx.x * 4 + q; n < N; n += gridDim.x * 4) {
        float acc = 0.f;
        if (isF32) {
            const float* xr = (const float*)x + (size_t)n * IN_CH;
            #pragma unroll 8
            for (int k = 0; k < IN_CH; ++k) acc += xr[k] * w[k * HID + c];
        } else {
            bf16p xr = (bf16p)x + (size_t)n * IN_CH;
            #pragma unroll 8
            for (int k = 0; k < IN_CH; ++k) acc += __bfloat162float(xr[k]) * w[k * HID + c];
        }
        h1b[(size_t)n * HID + c] = __float2bfloat16(acc);
    }
}

// ---- Fused aggregation1 (+self-loop+bias+ReLU) AND GEMM2: one wave per node.
//      Gather bf16 h1 (128 B/edge), g via LDS round-trip, h2 stored as bf16 40ch.
__global__ __launch_bounds__(256) void k_agg1gemm2(const int* rowstart, const int* erow,
        const __hip_bfloat16* h1b, const float* dinv, const float* b1f, const float* w2f,
        __hip_bfloat16* h2b, int N) {
    __shared__ float w2[HID * OUT_CH];   // 2560 floats
    __shared__ float sg[256];            // per-wave g slices
    for (int i = threadIdx.x; i < HID * OUT_CH; i += 256) w2[i] = w2f[i];
    __syncthreads();

    int w = (blockIdx.x * 256 + threadIdx.x) >> 6;
    int c = threadIdx.x & 63;
    bool act = (w < N);
    float g = 0.f;
    if (act) {
        int s0 = __builtin_amdgcn_readfirstlane(rowstart[w]);
        int s1 = __builtin_amdgcn_readfirstlane(rowstart[w + 1]);
        float d = dinv[w];
        float acc = __bfloat162float(h1b[(size_t)w * HID + c]) * d * d + b1f[c];
        int i = s0;
        for (; i + 1 < s1; i += 2) {
            int r0 = erow[i];     int r1 = erow[i + 1];
            float n0 = dinv[r0] * d;
            float n1 = dinv[r1] * d;
            float v0 = __bfloat162float(h1b[(size_t)r0 * HID + c]);
            float v1 = __bfloat162float(h1b[(size_t)r1 * HID + c]);
            acc += v0 * n0 + v1 * n1;
        }
        if (i < s1) {
            int r = erow[i];
            acc += __bfloat162float(h1b[(size_t)r * HID + c]) * (dinv[r] * d);
        }
        g = fmaxf(acc, 0.f);
    }
    sg[threadIdx.x] = g;
    __syncthreads();
    if (act && c < OUT_CH) {
        const float* gs = sg + (threadIdx.x & 192);   // this wave's 64-slice
        float acc2 = 0.f;
        #pragma unroll
        for (int k = 0; k < HID; ++k) acc2 += gs[k] * w2[k * OUT_CH + c];
        h2b[(size_t)w * OUT_CH + c] = __float2bfloat16(acc2);
    }
}

// ---- Aggregation 2 (CSR) on bf16 h2 (40ch, 80 B/edge gathers); +b2 -> f32 d_out
__global__ __launch_bounds__(256) void k_agg2(const int* rowstart, const int* erow,
        const __hip_bfloat16* h2b, const float* dinv, const float* b2f,
        float* out, int N) {
    int w = (blockIdx.x * 256 + threadIdx.x) >> 6;
    int c = threadIdx.x & 63;
    if (w >= N) return;
    int s0 = __builtin_amdgcn_readfirstlane(rowstart[w]);
    int s1 = __builtin_amdgcn_readfirstlane(rowstart[w + 1]);
    float d = dinv[w];
    float acc = 0.f;
    if (c < OUT_CH) acc = __bfloat162float(h2b[(size_t)w * OUT_CH + c]) * d * d + b2f[c];
    int i = s0;
    for (; i + 1 < s1; i += 2) {
        int r0 = erow[i];     int r1 = erow[i + 1];
        float n0 = dinv[r0] * d;
        float n1 = dinv[r1] * d;
        if (c < OUT_CH) {
            float v0 = __bfloat162float(h2b[(size_t)r0 * OUT_CH + c]);
            float v1 = __bfloat162float(h2b[(size_t)r1 * OUT_CH + c]);
            acc += v0 * n0 + v1 * n1;
        }
    }
    if (i < s1 && c < OUT_CH) {
        int r = erow[i];
        acc += __bfloat162float(h2b[(size_t)r * OUT_CH + c]) * (dinv[r] * d);
    }
    if (c < OUT_CH) out[(size_t)w * OUT_CH + c] = acc;
}

extern "C" void kernel_launch(void* const* d_in, const int* in_sizes, int n_in,
                              void* d_out, int out_size, void* d_ws, size_t ws_size,
                              hipStream_t stream) {
    const void* x  = d_in[0];
    const void* ei = d_in[1];
    const void* W1 = d_in[2];
    const void* b1 = d_in[3];
    const void* W2 = d_in[4];
    const void* b2 = d_in[5];
    const int N = in_sizes[0] / IN_CH;   // 100000
    const int E = in_sizes[1] / 2;       // 1600000
    const int* eii = (const int*)ei;
    const int NB = (N + 255) / 256;

    // ---- workspace layout (4-byte units). Peak ~29 MiB.
    float* ws = (float*)d_ws;
    size_t off = 16;
    int*   flags    = (int*)ws;
    int*   deg      = (int*)ws + off;            off += N;
    int*   fill     = (int*)ws + off;            off += N;
    float* dinv     = ws + off;                  off += N;
    float* wf       = ws + off;                  off += 10880;
    int*   bsum     = (int*)ws + off;            off += NB + 16;
    int*   rowstart = (int*)ws + off;            off += N + 1;
    off = (off + 255) & ~(size_t)255;
    int*   erow     = (int*)ws + off;            off += E;
    __hip_bfloat16* h1b = (__hip_bfloat16*)(ws + off);     off += (size_t)N * HID / 2;
    __hip_bfloat16* h2b = (__hip_bfloat16*)(ws + off);     off += (size_t)N * OUT_CH / 2;

    hipMemsetAsync(deg, 0, (size_t)N * sizeof(int), stream);  // deg only; fill pre-seeded

    k_detect<<<1, 256, 0, stream>>>(x, ei, flags);
    k_convw<<<(10856 + 255) / 256, 256, 0, stream>>>(W1, b1, W2, b2, flags, wf);
    k_deg<<<(E + 255) / 256, 256, 0, stream>>>(eii, flags, deg, E);
    k_dinv<<<(N + 255) / 256, 256, 0, stream>>>(deg, dinv, N);

    k_blocksum<<<NB, 256, 0, stream>>>(deg, bsum, N);
    k_scanbsum<<<1, 1024, 0, stream>>>(bsum, NB);
    k_scanfinal<<<NB, 256, 0, stream>>>(deg, bsum, rowstart, fill, N);
    k_scatter<<<4096, 256, 0, stream>>>(eii, flags, fill, erow, E, N);

    k_gemm1<<<4096, 256, 0, stream>>>(x, wf, h1b, flags, N);

    int nodeBlocks = (N * 64 + 255) / 256;   // 25000
    k_agg1gemm2<<<nodeBlocks, 256, 0, stream>>>(rowstart, erow, h1b, dinv,
                                                wf + 8192, wf + 8256, h2b, N);
    k_agg2<<<nodeBlocks, 256, 0, stream>>>(rowstart, erow, h2b, dinv,
                                           wf + 10816, (float*)d_out, N);
}